// Round 14
// baseline (1494.132 us; speedup 1.0000x reference)
//
#include <hip/hip_runtime.h>

// L2BoundedLTICell on MI355X (gfx950)
// B=16, T=4096, H=N=P=512, K_raw 1024x1024.
// out = [output (16x4096x512) | states (16x4097x512)] fp32.
//
// Structure (L=4 chunking, all GEMM, no sequential scan):
//   Zloc  = Ustack @ W4stack                  (16384 x 2048 x 512)
//   Zloc[b,0] += state @ Q4                   (tiny fixup GEMM)
//   KS: Z += shift(Z,d) @ Q_{4d}, d=1,2,4; round 3 writes states[.,4c+4,.]
//   phase C: states[t=4c+s] = [x_c; u_0..u_{s-1}] @ [Q_s ; Wtail], s=1..3
//   out = states_pre @ CT + u @ DT            (65536 x 1024 x 512)

typedef unsigned short u16;
typedef __bf16 bf16x8 __attribute__((ext_vector_type(8)));
typedef u16    u16x8  __attribute__((ext_vector_type(8)));
typedef float  f32x4  __attribute__((ext_vector_type(4)));

static_assert(sizeof(long) == 8, "need 64-bit long");

__device__ inline u16 f2bf(float f) {
    union { float f; unsigned u; } x; x.f = f;
    unsigned r = x.u + 0x7FFFu + ((x.u >> 16) & 1u);
    return (u16)(r >> 16);
}

__device__ inline bf16x8 cvt8(float4 v0, float4 v1) {
    bf16x8 a;
    a[0] = (__bf16)v0.x; a[1] = (__bf16)v0.y; a[2] = (__bf16)v0.z; a[3] = (__bf16)v0.w;
    a[4] = (__bf16)v1.x; a[5] = (__bf16)v1.y; a[6] = (__bf16)v1.z; a[7] = (__bf16)v1.w;
    return a;
}

// async global->LDS, 16B per lane; dest is wave-uniform base (HW adds lane*16)
__device__ inline void gl2lds16(const void* g, void* l) {
    auto gp = reinterpret_cast<const __attribute__((address_space(1))) char*>(
        (unsigned long long)g);
    auto lp = reinterpret_cast<__attribute__((address_space(3))) char*>(
        (unsigned)(unsigned long long)l);
    __builtin_amdgcn_global_load_lds(gp, lp, 16, 0, 0);
}

__device__ inline void wait_vmcnt(int n) {
    switch (n) {
        case 0:  asm volatile("s_waitcnt vmcnt(0)"  ::: "memory"); break;
        case 6:  asm volatile("s_waitcnt vmcnt(6)"  ::: "memory"); break;
        case 8:  asm volatile("s_waitcnt vmcnt(8)"  ::: "memory"); break;
        case 12: asm volatile("s_waitcnt vmcnt(12)" ::: "memory"); break;
        default: asm volatile("s_waitcnt vmcnt(0)"  ::: "memory"); break;
    }
}

// ---------------------------------------------------------------------------
// LDS-staged bf16 MFMA GEMM, N=512 fixed, K in 32-row chunks (panel layout).
// Counted-vmcnt pipeline (round-9/12 proven config: MF=1/2, (512,2)).
// sMode: FLAT grid 768, s = 3 - bx/256 (longest group first, contiguous s).
// ---------------------------------------------------------------------------
struct SArgs {
    const float* A1; long a1BS, a1RS; int a1Shift; unsigned a1Mask; int shiftA;
    int predLow; unsigned predMask;
    const float* A2; long a2BS, a2RS; int a2Shift; unsigned a2Mask;
    const u16* B1; const u16* B2;
    int K1c, Kc;
    const float* initP; long iBS, iRS; int iShift; unsigned iMask; float beta;
    float* Out; long oBS, oRS; int oShift; unsigned oMask;
    int sMode;
};

template<int MF>
__global__ __launch_bounds__(512, 2) void gemm_staged(SArgs g) {
    __shared__ char bstg[2][32768];
    const int tid = threadIdx.x, lane = tid & 63, wv = tid >> 6;
    const int kg = lane >> 4, l15 = lane & 15;
    const int rgw = wv >> 2, cg = wv & 3;
    const int cb = cg * 128;
    constexpr int LA = 2 * MF;           // global loads per loadA

    long bx = blockIdx.x;
    int Kc = g.Kc;
    const u16* B1 = g.B1;
    const u16* B2 = g.B2;
    float* Out = g.Out;
    if (g.sMode) {
        int s = 3 - (int)(bx >> 8);      // blocks 0-255: s=3 (longest, first)
        bx &= 255;
        Kc = g.K1c + 16 * s;
        B1 = g.B1 + (long)(s - 1) * 262144;
        B2 = g.B2 + (long)(4 - s) * 262144;
        Out = g.Out + (long)s * 512;
    }
    const long row0 = bx * (32 * MF) + rgw * (16 * MF);
    const int K1c = g.K1c;

    const float* ap1[MF]; const float* ap2[MF]; bool pr[MF];
#pragma unroll
    for (int mf = 0; mf < MF; ++mf) {
        unsigned r = (unsigned)(row0 + mf * 16 + l15);
        pr[mf] = (g.predLow == 0) || ((r & g.predMask) >= (unsigned)g.predLow);
        long ra = (long)r - g.shiftA; if (ra < 0) ra = 0;
        ap1[mf] = g.A1 + ((ra >> g.a1Shift) * g.a1BS) + ((ra & (long)g.a1Mask) * g.a1RS) + kg * 8;
        ap2[mf] = nullptr;
        if (g.A2)
            ap2[mf] = g.A2 + (((long)(r >> g.a2Shift)) * g.a2BS) + ((long)(r & g.a2Mask) * g.a2RS) + kg * 8;
    }

    f32x4 acc[MF][8];
    if (g.initP) {
#pragma unroll
        for (int mf = 0; mf < MF; ++mf)
#pragma unroll
            for (int q = 0; q < 4; ++q) {
                unsigned r = (unsigned)(row0 + mf * 16 + kg * 4 + q);
                const float* ip = g.initP + ((long)(r >> g.iShift)) * g.iBS
                                + ((long)(r & g.iMask)) * g.iRS + cb + l15;
#pragma unroll
                for (int nf = 0; nf < 8; ++nf)
                    acc[mf][nf][q] = g.beta * ip[nf * 16];
            }
    } else {
#pragma unroll
        for (int mf = 0; mf < MF; ++mf)
#pragma unroll
            for (int nf = 0; nf < 8; ++nf)
                acc[mf][nf] = (f32x4){0.f, 0.f, 0.f, 0.f};
    }

    auto stage = [&](int c) {
        const char* src = (const char*)((c < K1c) ? (B1 + (long)c * 16384)
                                                  : (B2 + (long)(c - K1c) * 16384));
        char* dst = bstg[c & 1];
        const int wo = wv << 12;
#pragma unroll
        for (int i = 0; i < 4; ++i)
            gl2lds16(src + wo + (i << 10) + (lane << 4), dst + wo + (i << 10));
    };

    auto loadA = [&](int c, float4* v0, float4* v1) {
        if (c < K1c) {
#pragma unroll
            for (int mf = 0; mf < MF; ++mf) {
                v0[mf] = *(const float4*)(ap1[mf]);
                v1[mf] = *(const float4*)(ap1[mf] + 4);
                ap1[mf] += 32;
            }
        } else {
#pragma unroll
            for (int mf = 0; mf < MF; ++mf) {
                v0[mf] = *(const float4*)(ap2[mf]);
                v1[mf] = *(const float4*)(ap2[mf] + 4);
                ap2[mf] += 32;
            }
        }
    };

    auto body = [&](int c, float4* v0, float4* v1, int buf, int wn) {
        bf16x8 af[MF];
        bool mk = (c < K1c);
#pragma unroll
        for (int mf = 0; mf < MF; ++mf) {
            bf16x8 a = cvt8(v0[mf], v1[mf]);
            if (mk && !pr[mf]) { u16x8 z = {0,0,0,0,0,0,0,0}; a = __builtin_bit_cast(bf16x8, z); }
            af[mf] = a;
        }
        if (c + 2 < Kc) loadA(c + 2, v0, v1);   // depth-2 register prefetch

        wait_vmcnt(wn);                          // stage(c) retired (this wave)
        __builtin_amdgcn_s_barrier();            // stage(c) visible (all waves)

        const char* bb = bstg[buf] + kg * 8192 + (cb + l15) * 16;
#pragma unroll
        for (int nf = 0; nf < 8; ++nf) {
            u16x8 br = *(const u16x8*)(bb + nf * 256);
            bf16x8 bv = __builtin_bit_cast(bf16x8, br);
#pragma unroll
            for (int mf = 0; mf < MF; ++mf)
                acc[mf][nf] = __builtin_amdgcn_mfma_f32_16x16x32_bf16(af[mf], bv, acc[mf][nf], 0, 0, 0);
        }

        asm volatile("s_waitcnt lgkmcnt(0)" ::: "memory");  // our ds_reads done
        __builtin_amdgcn_s_barrier();            // all waves done reading buf
        if (c + 2 < Kc) stage(c + 2);            // refill buf (no drain)
    };

    stage(0); stage(1);
    float4 a0v0[MF], a0v1[MF], a1v0[MF], a1v1[MF];
    loadA(0, a0v0, a0v1);
    loadA(1, a1v0, a1v1);

    for (int c = 0; c + 4 <= Kc; c += 2) {
        body(c,     a0v0, a0v1, 0, 2 * LA + 4);
        body(c + 1, a1v0, a1v1, 1, 2 * LA + 4);
    }
    body(Kc - 2, a0v0, a0v1, 0, LA + 4);
    body(Kc - 1, a1v0, a1v1, 1, 0);

#pragma unroll
    for (int mf = 0; mf < MF; ++mf)
#pragma unroll
        for (int q = 0; q < 4; ++q) {
            unsigned r = (unsigned)(row0 + mf * 16 + kg * 4 + q);
            float* op = Out + ((long)(r >> g.oShift)) * g.oBS
                      + ((long)(r & g.oMask)) * g.oRS + cb + l15;
#pragma unroll
            for (int nf = 0; nf < 8; ++nf) op[nf * 16] = acc[mf][nf][q];
        }
}

// ---------------------------------------------------------------------------
// global-B bf16 GEMM, 1-wave blocks (prep only): 16x128 tiles (r12 config).
// a1Panel mode: A1 is a bf16 panel (pLd = a1RS) of a SYMMETRIC matrix M —
// the contiguous u16x8 at ((k>>3)*pLd + r)*8 is M^T[r][k0..7] = M[r][k0..7].
// Used by the sigma chain (K^TK powers): 1x16B A-load replaces 2x float4 +
// 8 cvt, and the fp32 mirror write is dropped (Out==nullptr). For G0=K^T@K,
// the panel of K read as A gives K^T rows directly. Numerics bit-identical
// (fp32 path RNE-rounds to bf16 in-register; panel stores the same RNE).
// ---------------------------------------------------------------------------
struct GemmArgs {
    const float* A1; long a1RS; int shiftA;
    const u16*   Bp; long ldbN, colOff;
    const float* initP; long iRS; float beta;
    float* Out; long oRS;
    int Kit; int predLow;
    float* sumsq;
    const float* scalePtr; float cScale;
    u16* OutP; long opLd;
    int a1Panel;
};

__global__ __launch_bounds__(64) void gemm_bf16(GemmArgs g) {
    const int lane = threadIdx.x & 63;
    const int kg   = lane >> 4;
    const int l15  = lane & 15;
    const unsigned row0 = blockIdx.x * 16;
    const long cb = (long)blockIdx.y * 128;

    unsigned rA = row0 + l15;
    bool pr = (g.predLow == 0) || (rA >= (unsigned)g.predLow);
    long ra = (long)rA - g.shiftA; if (ra < 0) ra = 0;
    const float* ap = nullptr;
    const u16* apP = nullptr;
    long apStep = 0;
    if (g.a1Panel) {
        apP = (const u16*)g.A1 + ((long)kg * g.a1RS + ra) * 8;
        apStep = g.a1RS * 32;                 // 4 k-groups per iter, *8 u16
    } else {
        ap = g.A1 + ra * g.a1RS + kg * 8;
    }

    f32x4 acc[8];
#pragma unroll
    for (int nf = 0; nf < 8; ++nf) acc[nf] = (f32x4){0.f, 0.f, 0.f, 0.f};

    if (g.initP) {
#pragma unroll
        for (int q = 0; q < 4; ++q) {
            unsigned r = row0 + kg * 4 + q;
            const float* ip = g.initP + (long)r * g.iRS + cb + l15;
#pragma unroll
            for (int nf = 0; nf < 8; ++nf) acc[nf][q] = g.beta * ip[nf * 16];
        }
    }

    const u16* bp = g.Bp + ((long)kg * g.ldbN + g.colOff + cb + l15) * 8;
    const long bstep = g.ldbN * 32;

    for (int kk = 0; kk < g.Kit; ++kk) {
        bf16x8 a;
        if (g.a1Panel) {
            u16x8 araw = *(const u16x8*)apP;
            apP += apStep;
            a = __builtin_bit_cast(bf16x8, araw);
        } else {
            float4 v0 = *(const float4*)(ap);
            float4 v1 = *(const float4*)(ap + 4);
            ap += 32;
            a = cvt8(v0, v1);
        }
        if (!pr) { u16x8 z = {0,0,0,0,0,0,0,0}; a = __builtin_bit_cast(bf16x8, z); }
#pragma unroll
        for (int nf = 0; nf < 8; ++nf) {
            u16x8 braw = *(const u16x8*)(bp + (long)nf * 128);
            bf16x8 bb = __builtin_bit_cast(bf16x8, braw);
            acc[nf] = __builtin_amdgcn_mfma_f32_16x16x32_bf16(a, bb, acc[nf], 0, 0, 0);
        }
        bp += bstep;
    }

    float sc = g.cScale;
    if (g.scalePtr) sc *= 1.0f / g.scalePtr[0];
    float ss = 0.f;
#pragma unroll
    for (int q = 0; q < 4; ++q) {
        unsigned r = row0 + kg * 4 + q;
        float* op = g.Out ? (g.Out + (long)r * g.oRS + cb + l15) : nullptr;
#pragma unroll
        for (int nf = 0; nf < 8; ++nf) {
            float v = sc * acc[nf][q];
            if (op) op[nf * 16] = v;
            ss += v * v;
            if (g.OutP) {
                long col = cb + l15 + nf * 16;
                g.OutP[((long)(r >> 3) * g.opLd + col) * 8 + (r & 7)] = f2bf(v);
            }
        }
    }
    if (g.sumsq) {
#pragma unroll
        for (int off = 32; off; off >>= 1) ss += __shfl_down(ss, off);
        if (lane == 0) atomicAdd(g.sumsq, ss);
    }
}

// ---------------------------------------------------------------------------
// fp32 GEMM 512x512x512 (Newton polish only): O = alpha*A@B + beta*I
// ---------------------------------------------------------------------------
__global__ __launch_bounds__(256) void gemm_f32_512(const float* A, const float* B,
                                                    const float* I, float* O,
                                                    float alpha, float beta) {
    __shared__ float As[16][68];
    __shared__ float Bs[16][68];
    const int tx = threadIdx.x & 15, ty = threadIdx.x >> 4;
    const int bm = blockIdx.x * 64, bn = blockIdx.y * 64;
    float acc[4][4] = {};
    for (int k0 = 0; k0 < 512; k0 += 16) {
        for (int t = threadIdx.x; t < 1024; t += 256) {
            int r = t >> 4, c = t & 15;
            As[c][r] = A[(long)(bm + r) * 512 + k0 + c];
            int r2 = t >> 6, c2 = t & 63;
            Bs[r2][c2] = B[(long)(k0 + r2) * 512 + bn + c2];
        }
        __syncthreads();
#pragma unroll
        for (int k = 0; k < 16; ++k)
#pragma unroll
            for (int i = 0; i < 4; ++i)
#pragma unroll
                for (int j = 0; j < 4; ++j)
                    acc[i][j] += As[k][ty * 4 + i] * Bs[k][tx * 4 + j];
        __syncthreads();
    }
#pragma unroll
    for (int i = 0; i < 4; ++i)
#pragma unroll
        for (int j = 0; j < 4; ++j) {
            long o = (long)(bm + ty * 4 + i) * 512 + bn + tx * 4 + j;
            float v = alpha * acc[i][j];
            if (I) v += beta * I[o];
            O[o] = v;
        }
}

// ---------------------------------------------------------------------------
// small utility kernels
// ---------------------------------------------------------------------------
__global__ __launch_bounds__(256) void k_cast_panel(const float* src, long srcLd, long R, long C,
                                                    u16* panel, long pLd) {
    long total = R * C;
    for (long idx = (long)blockIdx.x * 256 + threadIdx.x; idx < total; idx += (long)gridDim.x * 256) {
        long k = idx / C, n = idx % C;
        panel[((k >> 3) * pLd + n) * 8 + (k & 7)] = f2bf(src[k * srcLd + n]);
    }
}

__global__ __launch_bounds__(256) void k_transpose_cast(const float* src, long srcLd, long R, long C,
                                                        u16* panel, long pLd, float* dstFT,
                                                        const float* slots, int sIdx) {
    float scale = (sIdx >= 0) ? slots[sIdx] : 1.0f;
    long total = R * C;
    for (long idx = (long)blockIdx.x * 256 + threadIdx.x; idx < total; idx += (long)gridDim.x * 256) {
        long i = idx / C, j = idx % C;
        float v = src[i * srcLd + j] * scale;
        if (panel) panel[((j >> 3) * pLd + i) * 8 + (j & 7)] = f2bf(v);
        if (dstFT) dstFT[j * R + i] = v;
    }
}

// 4 fused 512x512 scaled transposes (panel + optional fp32 transpose out)
struct T4Args {
    const float* src0; const float* src1; const float* src2; const float* src3;
    long ld0, ld1, ld2, ld3;
    u16 *p0, *p1, *p2, *p3;
    float *f0, *f1, *f2, *f3;
    int s0, s1, s2, s3;
    const float* slots;
};
__global__ __launch_bounds__(256) void k_transpose4(T4Args t) {
    int m = blockIdx.y;
    const float* src; long ld; u16* panel; float* dstFT; int sIdx;
    if (m == 0) { src = t.src0; ld = t.ld0; panel = t.p0; dstFT = t.f0; sIdx = t.s0; }
    else if (m == 1) { src = t.src1; ld = t.ld1; panel = t.p1; dstFT = t.f1; sIdx = t.s1; }
    else if (m == 2) { src = t.src2; ld = t.ld2; panel = t.p2; dstFT = t.f2; sIdx = t.s2; }
    else { src = t.src3; ld = t.ld3; panel = t.p3; dstFT = t.f3; sIdx = t.s3; }
    float scale = (sIdx >= 0) ? t.slots[sIdx] : 1.0f;
    for (long idx = (long)blockIdx.x * 256 + threadIdx.x; idx < 262144; idx += (long)gridDim.x * 256) {
        long i = idx >> 9, j = idx & 511;
        float v = src[i * ld + j] * scale;
        panel[((j >> 3) * 512 + i) * 8 + (j & 7)] = f2bf(v);
        if (dstFT) dstFT[j * 512 + i] = v;
    }
}

// S panel cast + X1 = 2I - S (fp32 + panel), fused
__global__ __launch_bounds__(256) void k_sx1(const float* S, u16* Sp, float* Xf, u16* Xp) {
    for (long idx = (long)blockIdx.x * 256 + threadIdx.x; idx < 262144; idx += (long)gridDim.x * 256) {
        int i = (int)(idx >> 9), j = (int)(idx & 511);
        float sv = S[idx];
        Sp[(((long)(i >> 3)) * 512 + j) * 8 + (i & 7)] = f2bf(sv);
        float v = ((i == j) ? 2.0f : 0.0f) - sv;
        Xf[idx] = v;
        Xp[(((long)(i >> 3)) * 512 + j) * 8 + (i & 7)] = f2bf(v);
    }
}

__global__ void k_fin(float* slots, const float* lg) {
    float lnacc = 0.f, w = 1.f;
    for (int i = 0; i <= 8; ++i) {
        lnacc += w * 0.5f * logf(fmaxf(slots[i], 1e-30f));
        w *= 0.5f;
    }
    float sigma = fmaxf(expf(0.5f * lnacc), 1e-5f);
    float s = sigma + 0.002f;
    slots[32] = 1.0f / s;            // s_inv
    slots[33] = expf(lg[0]) / s;     // gamma * s_inv
}

__global__ __launch_bounds__(256) void k_state0(float* states, const float* state) {
    int i = blockIdx.x * 256 + threadIdx.x;
    if (i < 8192) {
        int b = i >> 9, n = i & 511;
        states[(long)b * 2097664 + n] = state[i];
    }
}

// ---------------------------------------------------------------------------
extern "C" void kernel_launch(void* const* d_in, const int* in_sizes, int n_in,
                              void* d_out, int out_size, void* d_ws, size_t ws_size,
                              hipStream_t stream) {
    (void)in_sizes; (void)n_in; (void)out_size; (void)ws_size;

    const float* u     = (const float*)d_in[0];   // 16 x 4096 x 512
    const float* state = (const float*)d_in[1];   // 16 x 512
    const float* S     = (const float*)d_in[2];   // 512 x 512
    const float* K     = (const float*)d_in[3];   // 1024 x 1024
    const float* lg    = (const float*)d_in[4];   // scalar

    float* out    = (float*)d_out;                // 16 x 4096 x 512
    float* states = out + 33554432L;              // 16 x 4097 x 512
    float* Zb     = out;                          // KS ping (16384x512), overwritten by out-GEMM

    // workspace: persistent panels, then scratch (Za aliases scratch start)
    char* w = (char*)d_ws;
    auto alloc = [&](size_t n) { void* p = w; w += (n + 255) & ~(size_t)255; return p; };
    float* slots = (float*)alloc(256);
    u16* Qall = (u16*)alloc(4L * 262144 * 2);   // Q1..Q4 panels (block p-1 = AT^p)
    u16* W4p  = (u16*)alloc(4L * 262144 * 2);   // W_p = BT@AT^(3-p), p=0..3
    u16* Q8p  = (u16*)alloc(262144L * 2);
    u16* Q16p = (u16*)alloc(262144L * 2);
    u16* CDT  = (u16*)alloc(2L * 262144 * 2);   // [CT;DT]
    float* Qf   = (float*)alloc(4L * 262144 * 4); // Q1..Q4 fp32
    float* W4f  = (float*)alloc(4L * 262144 * 4); // W0..W3 fp32
    float* Q8f  = (float*)alloc(262144L * 4);
    float* Q16f = (float*)alloc(262144L * 4);
    float* Za   = (float*)w;                      // 16384x512 fp32 (32MB), aliases scratch
    u16*   Kp  = (u16*)  alloc(1024L * 1024 * 2);
    u16*   Mp  = (u16*)  alloc(1024L * 1024 * 2);
    u16*   Mp2 = (u16*)  alloc(1024L * 1024 * 2);
    u16*   Sp  = (u16*)  alloc(512L * 512 * 2);
    float* Xaf = (float*)alloc(512L * 512 * 4);
    u16*   Xap = (u16*)  alloc(512L * 512 * 2);
    float* Xbf = (float*)alloc(512L * 512 * 4);
    u16*   Xbp = (u16*)  alloc(512L * 512 * 2);
    float* Pf  = (float*)alloc(512L * 512 * 4);
    u16*   Pp  = (u16*)  alloc(512L * 512 * 2);
    float* Xs  = (float*)alloc(512L * 512 * 4);
    float* T1f = (float*)alloc(1024L * 512 * 4); // [K11@S ; K21@S]
    u16*   T1p = (u16*)  alloc(1024L * 512 * 2); // panel (rows 0..511 = K11@S)
    float* Cmf = T1f + 262144;                   // alias: bottom half = K21@S
    float* Af  = (float*)alloc(512L * 512 * 4);
    float* Bmf = (float*)alloc(512L * 512 * 4);

    auto mkargs = [&]() { GemmArgs a = {}; a.beta = 1.f; a.cScale = 1.f; return a; };
    auto launch_gemm = [&](int M, int N, const GemmArgs& a) {
        dim3 gr(M / 16, N / 128);
        gemm_bf16<<<gr, 64, 0, stream>>>(a);
    };

    hipMemsetAsync(slots, 0, 256, stream);

    // ---- sigma = ||K||_2 via normalized repeated squaring of K^T K --------
    // All sigma-chain operands are symmetric -> A read directly from bf16
    // panels (panel-of-K as A == K^T rows). No fp32 mirrors, no KT transpose.
    k_cast_panel<<<4096, 256, 0, stream>>>(K, 1024, 1024, 1024, Kp, 1024);
    {   GemmArgs a = mkargs();                   // G0 = K^T @ K
        a.A1 = (const float*)Kp; a.a1Panel = 1; a.a1RS = 1024;
        a.Bp = Kp; a.ldbN = 1024;
        a.Out = nullptr; a.oRS = 1024; a.OutP = Mp; a.opLd = 1024;
        a.Kit = 32; a.sumsq = slots + 0;
        launch_gemm(1024, 1024, a);
    }
    {   u16* Ps[2] = {Mp, Mp2};
        for (int i = 1; i <= 8; ++i) {           // P_i = (P_{i-1}/s_{i-1})^2
            GemmArgs a = mkargs();
            a.A1 = (const float*)Ps[(i + 1) & 1]; a.a1Panel = 1; a.a1RS = 1024;
            a.Bp = Ps[(i + 1) & 1]; a.ldbN = 1024;
            a.Out = nullptr; a.oRS = 1024; a.OutP = Ps[i & 1]; a.opLd = 1024;
            a.Kit = 32; a.sumsq = slots + i; a.scalePtr = slots + (i - 1);
            launch_gemm(1024, 1024, a);
        }
    }
    k_fin<<<1, 1, 0, stream>>>(slots, lg);

    // ---- Sinv via Newton (3 bf16 iters + 1 fp32 polish) --------------------
    k_sx1<<<1024, 256, 0, stream>>>(S, Sp, Xaf, Xap);
    float* curF = Xaf; u16* curP = Xap; float* nxtF = Xbf; u16* nxtP = Xbp;
    for (int it = 0; it < 3; ++it) {
        GemmArgs a = mkargs();
        a.A1 = S; a.a1RS = 512;
        a.Bp = curP; a.ldbN = 512;
        a.Out = Pf; a.oRS = 512; a.OutP = Pp; a.opLd = 512; a.cScale = -1.f;
        a.Kit = 16;
        launch_gemm(512, 512, a);
        GemmArgs b = mkargs();
        b.A1 = curF; b.a1RS = 512;
        b.Bp = Pp; b.ldbN = 512;
        b.initP = curF; b.iRS = 512; b.beta = 2.f;
        b.Out = nxtF; b.oRS = 512; b.OutP = nxtP; b.opLd = 512;
        b.Kit = 16;
        launch_gemm(512, 512, b);
        float* tf = curF; curF = nxtF; nxtF = tf;
        u16*   tp = curP; curP = nxtP; nxtP = tp;
    }
    gemm_f32_512<<<dim3(8, 8), 256, 0, stream>>>(S, curF, nullptr, Pf, 1.f, 0.f);
    gemm_f32_512<<<dim3(8, 8), 256, 0, stream>>>(curF, Pf, curF, Xs, -1.f, 2.f);

    // ---- A,B,C,D prep ------------------------------------------------------
    {   GemmArgs a = mkargs();   // [T1;Cmf] = [K11;K21] @ S   (merged, M=1024)
        a.A1 = K; a.a1RS = 1024; a.Bp = Sp; a.ldbN = 512;
        a.Out = T1f; a.oRS = 512; a.OutP = T1p; a.opLd = 512; a.Kit = 16;
        launch_gemm(1024, 512, a);
    }
    {   GemmArgs a = mkargs();   // Af = Sinv @ T1  (T1p rows 0..511 = K11@S)
        a.A1 = Xs; a.a1RS = 512; a.Bp = T1p; a.ldbN = 512;
        a.Out = Af; a.oRS = 512; a.Kit = 16;
        launch_gemm(512, 512, a);
    }
    {   GemmArgs a = mkargs();   // Bmf = Sinv @ K12
        a.A1 = Xs; a.a1RS = 512; a.Bp = Kp; a.ldbN = 1024; a.colOff = 512;
        a.Out = Bmf; a.oRS = 512; a.Kit = 16;
        launch_gemm(512, 512, a);
    }
    // fused transposes: Q1 = AT*sinv; W3 = BT*g*sinv; CT*sinv; DT*g*sinv
    {   T4Args t = {};
        t.src0 = Af;  t.ld0 = 512;  t.p0 = Qall;            t.f0 = Qf;             t.s0 = 32;
        t.src1 = Bmf; t.ld1 = 512;  t.p1 = W4p + 3*262144;  t.f1 = W4f + 3*262144; t.s1 = 33;
        t.src2 = Cmf; t.ld2 = 512;  t.p2 = CDT;             t.f2 = nullptr;        t.s2 = 32;
        t.src3 = K + 512L*1024 + 512; t.ld3 = 1024; t.p3 = CDT + 262144; t.f3 = nullptr; t.s3 = 33;
        t.slots = slots;
        k_transpose4<<<dim3(512, 4), 256, 0, stream>>>(t);
    }
    // Q chain: Q2; [Q3;Q4]; Q8; Q16
    {   GemmArgs a = mkargs();
        a.A1 = Qf; a.a1RS = 512; a.Bp = Qall; a.ldbN = 512;
        a.Out = Qf + 262144; a.oRS = 512; a.OutP = Qall + 262144; a.opLd = 512; a.Kit = 16;
        launch_gemm(512, 512, a);                                   // Q2
        a.A1 = Qf; a.Bp = Qall + 262144;
        a.Out = Qf + 2 * 262144; a.OutP = Qall + 2 * 262144;
        launch_gemm(1024, 512, a);                                  // [Q3;Q4]
        a.A1 = Qf + 3 * 262144; a.Bp = Qall + 3 * 262144;
        a.Out = Q8f; a.OutP = Q8p;
        launch_gemm(512, 512, a);                                   // Q8
        a.A1 = Q8f; a.Bp = Q8p;
        a.Out = Q16f; a.OutP = Q16p;
        launch_gemm(512, 512, a);                                   // Q16
    }
    // W chain: W2 = BT@AT; [W0;W1] = [W2;W3]@Q2
    {   GemmArgs a = mkargs();
        a.A1 = W4f + 3 * 262144; a.a1RS = 512; a.Bp = Qall; a.ldbN = 512;
        a.Out = W4f + 2 * 262144; a.oRS = 512; a.OutP = W4p + 2 * 262144; a.opLd = 512; a.Kit = 16;
        launch_gemm(512, 512, a);                                   // W2
        a.A1 = W4f + 2 * 262144; a.Bp = Qall + 262144;
        a.Out = W4f; a.OutP = W4p;
        launch_gemm(1024, 512, a);                                  // [W0;W1]
    }

    // ---- Zloc = Ustack @ W4stack  (16384 x 2048 x 512), MF=1: 512 blocks ---
    {   SArgs a = {};
        a.A1 = u; a.a1BS = 2097152; a.a1RS = 2048; a.a1Shift = 10; a.a1Mask = 1023;
        a.predMask = 1023;
        a.B1 = W4p; a.B2 = W4p; a.K1c = 64; a.Kc = 64;
        a.beta = 1.f;
        a.Out = Za; a.oBS = 0; a.oRS = 512; a.oShift = 14; a.oMask = 16383;
        gemm_staged<1><<<dim3(512, 1, 1), 512, 0, stream>>>(a);
    }
    // state fixup: Zloc[b,0] += state @ Q4
    {   GemmArgs f = mkargs();
        f.A1 = state; f.a1RS = 512;
        f.Bp = Qall + 3 * 262144; f.ldbN = 512;
        f.initP = Za; f.iRS = 524288; f.beta = 1.f;
        f.Out = Za; f.oRS = 524288; f.Kit = 16;
        launch_gemm(16, 512, f);
    }
    k_state0<<<32, 256, 0, stream>>>(states, state);

    // ---- Kogge-Stone: rounds d=1 (Q4), d=2 (Q8); round d=4 (Q16) -> states -
    auto ks = [&](const float* src, float* dst, int d, const u16* gen) {
        SArgs a = {};
        a.A1 = src; a.a1BS = 0; a.a1RS = 512; a.a1Shift = 14; a.a1Mask = 16383;
        a.shiftA = d; a.predLow = d; a.predMask = 1023;
        a.B1 = gen; a.B2 = gen; a.K1c = 16; a.Kc = 16;
        a.initP = src; a.iBS = 0; a.iRS = 512; a.iShift = 14; a.iMask = 16383; a.beta = 1.f;
        a.Out = dst; a.oBS = 0; a.oRS = 512; a.oShift = 14; a.oMask = 16383;
        gemm_staged<1><<<dim3(512, 1, 1), 512, 0, stream>>>(a);
    };
    ks(Za, Zb, 1, Qall + 3 * 262144);
    ks(Zb, Za, 2, Q8p);
    {   // round 3: dst = states[b][4c+4] (strided)
        SArgs a = {};
        a.A1 = Za; a.a1BS = 0; a.a1RS = 512; a.a1Shift = 14; a.a1Mask = 16383;
        a.shiftA = 4; a.predLow = 4; a.predMask = 1023;
        a.B1 = Q16p; a.B2 = Q16p; a.K1c = 16; a.Kc = 16;
        a.initP = Za; a.iBS = 0; a.iRS = 512; a.iShift = 14; a.iMask = 16383; a.beta = 1.f;
        a.Out = states + 2048; a.oBS = 2097664; a.oRS = 2048; a.oShift = 10; a.oMask = 1023;
        gemm_staged<1><<<dim3(512, 1, 1), 512, 0, stream>>>(a);
    }

    // ---- phase C: states[4c+s] = [x_c; u_0..u_{s-1}] @ [Q_s; Wtail], s=1..3 -
    // flat grid 768, s = 3 - bx/256 (longest group first, contiguous s)
    {   SArgs a = {};
        a.A1 = states; a.a1BS = 2097664; a.a1RS = 2048; a.a1Shift = 10; a.a1Mask = 1023;
        a.predMask = 1023;
        a.A2 = u; a.a2BS = 2097152; a.a2RS = 2048; a.a2Shift = 10; a.a2Mask = 1023;
        a.B1 = Qall; a.B2 = W4p; a.K1c = 16; a.Kc = 0;
        a.beta = 1.f;
        a.Out = states; a.oBS = 2097664; a.oRS = 2048; a.oShift = 10; a.oMask = 1023;
        a.sMode = 1;
        gemm_staged<2><<<dim3(768, 1, 1), 512, 0, stream>>>(a);
    }

    // ---- out = states_pre @ CT + u @ DT  (65536 x 1024 x 512), MF=2 --------
    {   SArgs a = {};
        a.A1 = states; a.a1BS = 2097664; a.a1RS = 512; a.a1Shift = 12; a.a1Mask = 4095;
        a.predMask = 4095;
        a.A2 = u; a.a2BS = 2097152; a.a2RS = 512; a.a2Shift = 12; a.a2Mask = 4095;
        a.B1 = CDT; a.B2 = CDT + 262144; a.K1c = 16; a.Kc = 32;
        a.beta = 1.f;
        a.Out = out; a.oBS = 2097152; a.oRS = 512; a.oShift = 12; a.oMask = 4095;
        gemm_staged<2><<<dim3(1024, 1, 1), 512, 0, stream>>>(a);
    }
}

// Round 15
// 1196.498 us; speedup vs baseline: 1.2488x; 1.2488x over previous
//
#include <hip/hip_runtime.h>

// L2BoundedLTICell on MI355X (gfx950)
// B=16, T=4096, H=N=P=512, K_raw 1024x1024.
// out = [output (16x4096x512) | states (16x4097x512)] fp32.
//
// Structure (L=4 chunking, all GEMM, no sequential scan):
//   Zloc  = Ustack @ W4stack                  (16384 x 2048 x 512)
//   Zloc[b,0] += state @ Q4                   (tiny fixup GEMM)
//   KS: Z += shift(Z,d) @ Q_{4d}, d=1,2,4; round 3 writes states[.,4c+4,.]
//   phase C: states[t=4c+s] = [x_c; u_0..u_{s-1}] @ [Q_s ; Wtail], s=1..3
//   out = states_pre @ CT + u @ DT            (65536 x 1024 x 512)
//
// This is the round-12 configuration (best verified: 1197us), restored
// verbatim after rounds 13/14 prep experiments regressed.

typedef unsigned short u16;
typedef __bf16 bf16x8 __attribute__((ext_vector_type(8)));
typedef u16    u16x8  __attribute__((ext_vector_type(8)));
typedef float  f32x4  __attribute__((ext_vector_type(4)));

static_assert(sizeof(long) == 8, "need 64-bit long");

__device__ inline u16 f2bf(float f) {
    union { float f; unsigned u; } x; x.f = f;
    unsigned r = x.u + 0x7FFFu + ((x.u >> 16) & 1u);
    return (u16)(r >> 16);
}

__device__ inline bf16x8 cvt8(float4 v0, float4 v1) {
    bf16x8 a;
    a[0] = (__bf16)v0.x; a[1] = (__bf16)v0.y; a[2] = (__bf16)v0.z; a[3] = (__bf16)v0.w;
    a[4] = (__bf16)v1.x; a[5] = (__bf16)v1.y; a[6] = (__bf16)v1.z; a[7] = (__bf16)v1.w;
    return a;
}

// async global->LDS, 16B per lane; dest is wave-uniform base (HW adds lane*16)
__device__ inline void gl2lds16(const void* g, void* l) {
    auto gp = reinterpret_cast<const __attribute__((address_space(1))) char*>(
        (unsigned long long)g);
    auto lp = reinterpret_cast<__attribute__((address_space(3))) char*>(
        (unsigned)(unsigned long long)l);
    __builtin_amdgcn_global_load_lds(gp, lp, 16, 0, 0);
}

__device__ inline void wait_vmcnt(int n) {
    switch (n) {
        case 0:  asm volatile("s_waitcnt vmcnt(0)"  ::: "memory"); break;
        case 6:  asm volatile("s_waitcnt vmcnt(6)"  ::: "memory"); break;
        case 8:  asm volatile("s_waitcnt vmcnt(8)"  ::: "memory"); break;
        case 12: asm volatile("s_waitcnt vmcnt(12)" ::: "memory"); break;
        default: asm volatile("s_waitcnt vmcnt(0)"  ::: "memory"); break;
    }
}

// ---------------------------------------------------------------------------
// LDS-staged bf16 MFMA GEMM, N=512 fixed, K in 32-row chunks (panel layout).
// Counted-vmcnt pipeline (round-9 proven config: MF=1/2, (512,2)).
// sMode: FLAT grid 768, s = 3 - bx/256 (longest group first, contiguous s).
// ---------------------------------------------------------------------------
struct SArgs {
    const float* A1; long a1BS, a1RS; int a1Shift; unsigned a1Mask; int shiftA;
    int predLow; unsigned predMask;
    const float* A2; long a2BS, a2RS; int a2Shift; unsigned a2Mask;
    const u16* B1; const u16* B2;
    int K1c, Kc;
    const float* initP; long iBS, iRS; int iShift; unsigned iMask; float beta;
    float* Out; long oBS, oRS; int oShift; unsigned oMask;
    int sMode;
};

template<int MF>
__global__ __launch_bounds__(512, 2) void gemm_staged(SArgs g) {
    __shared__ char bstg[2][32768];
    const int tid = threadIdx.x, lane = tid & 63, wv = tid >> 6;
    const int kg = lane >> 4, l15 = lane & 15;
    const int rgw = wv >> 2, cg = wv & 3;
    const int cb = cg * 128;
    constexpr int LA = 2 * MF;           // global loads per loadA

    long bx = blockIdx.x;
    int Kc = g.Kc;
    const u16* B1 = g.B1;
    const u16* B2 = g.B2;
    float* Out = g.Out;
    if (g.sMode) {
        int s = 3 - (int)(bx >> 8);      // blocks 0-255: s=3 (longest, first)
        bx &= 255;
        Kc = g.K1c + 16 * s;
        B1 = g.B1 + (long)(s - 1) * 262144;
        B2 = g.B2 + (long)(4 - s) * 262144;
        Out = g.Out + (long)s * 512;
    }
    const long row0 = bx * (32 * MF) + rgw * (16 * MF);
    const int K1c = g.K1c;

    const float* ap1[MF]; const float* ap2[MF]; bool pr[MF];
#pragma unroll
    for (int mf = 0; mf < MF; ++mf) {
        unsigned r = (unsigned)(row0 + mf * 16 + l15);
        pr[mf] = (g.predLow == 0) || ((r & g.predMask) >= (unsigned)g.predLow);
        long ra = (long)r - g.shiftA; if (ra < 0) ra = 0;
        ap1[mf] = g.A1 + ((ra >> g.a1Shift) * g.a1BS) + ((ra & (long)g.a1Mask) * g.a1RS) + kg * 8;
        ap2[mf] = nullptr;
        if (g.A2)
            ap2[mf] = g.A2 + (((long)(r >> g.a2Shift)) * g.a2BS) + ((long)(r & g.a2Mask) * g.a2RS) + kg * 8;
    }

    f32x4 acc[MF][8];
    if (g.initP) {
#pragma unroll
        for (int mf = 0; mf < MF; ++mf)
#pragma unroll
            for (int q = 0; q < 4; ++q) {
                unsigned r = (unsigned)(row0 + mf * 16 + kg * 4 + q);
                const float* ip = g.initP + ((long)(r >> g.iShift)) * g.iBS
                                + ((long)(r & g.iMask)) * g.iRS + cb + l15;
#pragma unroll
                for (int nf = 0; nf < 8; ++nf)
                    acc[mf][nf][q] = g.beta * ip[nf * 16];
            }
    } else {
#pragma unroll
        for (int mf = 0; mf < MF; ++mf)
#pragma unroll
            for (int nf = 0; nf < 8; ++nf)
                acc[mf][nf] = (f32x4){0.f, 0.f, 0.f, 0.f};
    }

    auto stage = [&](int c) {
        const char* src = (const char*)((c < K1c) ? (B1 + (long)c * 16384)
                                                  : (B2 + (long)(c - K1c) * 16384));
        char* dst = bstg[c & 1];
        const int wo = wv << 12;
#pragma unroll
        for (int i = 0; i < 4; ++i)
            gl2lds16(src + wo + (i << 10) + (lane << 4), dst + wo + (i << 10));
    };

    auto loadA = [&](int c, float4* v0, float4* v1) {
        if (c < K1c) {
#pragma unroll
            for (int mf = 0; mf < MF; ++mf) {
                v0[mf] = *(const float4*)(ap1[mf]);
                v1[mf] = *(const float4*)(ap1[mf] + 4);
                ap1[mf] += 32;
            }
        } else {
#pragma unroll
            for (int mf = 0; mf < MF; ++mf) {
                v0[mf] = *(const float4*)(ap2[mf]);
                v1[mf] = *(const float4*)(ap2[mf] + 4);
                ap2[mf] += 32;
            }
        }
    };

    auto body = [&](int c, float4* v0, float4* v1, int buf, int wn) {
        bf16x8 af[MF];
        bool mk = (c < K1c);
#pragma unroll
        for (int mf = 0; mf < MF; ++mf) {
            bf16x8 a = cvt8(v0[mf], v1[mf]);
            if (mk && !pr[mf]) { u16x8 z = {0,0,0,0,0,0,0,0}; a = __builtin_bit_cast(bf16x8, z); }
            af[mf] = a;
        }
        if (c + 2 < Kc) loadA(c + 2, v0, v1);   // depth-2 register prefetch

        wait_vmcnt(wn);                          // stage(c) retired (this wave)
        __builtin_amdgcn_s_barrier();            // stage(c) visible (all waves)

        const char* bb = bstg[buf] + kg * 8192 + (cb + l15) * 16;
#pragma unroll
        for (int nf = 0; nf < 8; ++nf) {
            u16x8 br = *(const u16x8*)(bb + nf * 256);
            bf16x8 bv = __builtin_bit_cast(bf16x8, br);
#pragma unroll
            for (int mf = 0; mf < MF; ++mf)
                acc[mf][nf] = __builtin_amdgcn_mfma_f32_16x16x32_bf16(af[mf], bv, acc[mf][nf], 0, 0, 0);
        }

        asm volatile("s_waitcnt lgkmcnt(0)" ::: "memory");  // our ds_reads done
        __builtin_amdgcn_s_barrier();            // all waves done reading buf
        if (c + 2 < Kc) stage(c + 2);            // refill buf (no drain)
    };

    stage(0); stage(1);
    float4 a0v0[MF], a0v1[MF], a1v0[MF], a1v1[MF];
    loadA(0, a0v0, a0v1);
    loadA(1, a1v0, a1v1);

    for (int c = 0; c + 4 <= Kc; c += 2) {
        body(c,     a0v0, a0v1, 0, 2 * LA + 4);
        body(c + 1, a1v0, a1v1, 1, 2 * LA + 4);
    }
    body(Kc - 2, a0v0, a0v1, 0, LA + 4);
    body(Kc - 1, a1v0, a1v1, 1, 0);

#pragma unroll
    for (int mf = 0; mf < MF; ++mf)
#pragma unroll
        for (int q = 0; q < 4; ++q) {
            unsigned r = (unsigned)(row0 + mf * 16 + kg * 4 + q);
            float* op = Out + ((long)(r >> g.oShift)) * g.oBS
                      + ((long)(r & g.oMask)) * g.oRS + cb + l15;
#pragma unroll
            for (int nf = 0; nf < 8; ++nf) op[nf * 16] = acc[mf][nf][q];
        }
}

// ---------------------------------------------------------------------------
// global-B bf16 GEMM, 1-wave blocks (prep only): grid (M/16, N/128).
// ---------------------------------------------------------------------------
struct GemmArgs {
    const float* A1; long a1RS; int shiftA;
    const u16*   Bp; long ldbN, colOff;
    const float* initP; long iRS; float beta;
    float* Out; long oRS;
    int Kit; int predLow;
    float* sumsq;
    const float* scalePtr; float cScale;
    u16* OutP; long opLd;
};

__global__ __launch_bounds__(64) void gemm_bf16(GemmArgs g) {
    const int lane = threadIdx.x & 63;
    const int kg   = lane >> 4;
    const int l15  = lane & 15;
    const unsigned row0 = blockIdx.x * 16;
    const long cb = (long)blockIdx.y * 128;

    unsigned rA = row0 + l15;
    bool pr = (g.predLow == 0) || (rA >= (unsigned)g.predLow);
    long ra = (long)rA - g.shiftA; if (ra < 0) ra = 0;
    const float* ap = g.A1 + ra * g.a1RS + kg * 8;

    f32x4 acc[8];
#pragma unroll
    for (int nf = 0; nf < 8; ++nf) acc[nf] = (f32x4){0.f, 0.f, 0.f, 0.f};

    if (g.initP) {
#pragma unroll
        for (int q = 0; q < 4; ++q) {
            unsigned r = row0 + kg * 4 + q;
            const float* ip = g.initP + (long)r * g.iRS + cb + l15;
#pragma unroll
            for (int nf = 0; nf < 8; ++nf) acc[nf][q] = g.beta * ip[nf * 16];
        }
    }

    const u16* bp = g.Bp + ((long)kg * g.ldbN + g.colOff + cb + l15) * 8;
    const long bstep = g.ldbN * 32;

    for (int kk = 0; kk < g.Kit; ++kk) {
        float4 v0 = *(const float4*)(ap);
        float4 v1 = *(const float4*)(ap + 4);
        ap += 32;
        bf16x8 a = cvt8(v0, v1);
        if (!pr) { u16x8 z = {0,0,0,0,0,0,0,0}; a = __builtin_bit_cast(bf16x8, z); }
#pragma unroll
        for (int nf = 0; nf < 8; ++nf) {
            u16x8 braw = *(const u16x8*)(bp + (long)nf * 128);
            bf16x8 bb = __builtin_bit_cast(bf16x8, braw);
            acc[nf] = __builtin_amdgcn_mfma_f32_16x16x32_bf16(a, bb, acc[nf], 0, 0, 0);
        }
        bp += bstep;
    }

    float sc = g.cScale;
    if (g.scalePtr) sc *= 1.0f / g.scalePtr[0];
    float ss = 0.f;
#pragma unroll
    for (int q = 0; q < 4; ++q) {
        unsigned r = row0 + kg * 4 + q;
        float* op = g.Out + (long)r * g.oRS + cb + l15;
#pragma unroll
        for (int nf = 0; nf < 8; ++nf) {
            float v = sc * acc[nf][q];
            op[nf * 16] = v;
            ss += v * v;
            if (g.OutP) {
                long col = cb + l15 + nf * 16;
                g.OutP[((long)(r >> 3) * g.opLd + col) * 8 + (r & 7)] = f2bf(v);
            }
        }
    }
    if (g.sumsq) {
#pragma unroll
        for (int off = 32; off; off >>= 1) ss += __shfl_down(ss, off);
        if (lane == 0) atomicAdd(g.sumsq, ss);
    }
}

// ---------------------------------------------------------------------------
// fp32 GEMM 512x512x512 (Newton polish only): O = alpha*A@B + beta*I
// ---------------------------------------------------------------------------
__global__ __launch_bounds__(256) void gemm_f32_512(const float* A, const float* B,
                                                    const float* I, float* O,
                                                    float alpha, float beta) {
    __shared__ float As[16][68];
    __shared__ float Bs[16][68];
    const int tx = threadIdx.x & 15, ty = threadIdx.x >> 4;
    const int bm = blockIdx.x * 64, bn = blockIdx.y * 64;
    float acc[4][4] = {};
    for (int k0 = 0; k0 < 512; k0 += 16) {
        for (int t = threadIdx.x; t < 1024; t += 256) {
            int r = t >> 4, c = t & 15;
            As[c][r] = A[(long)(bm + r) * 512 + k0 + c];
            int r2 = t >> 6, c2 = t & 63;
            Bs[r2][c2] = B[(long)(k0 + r2) * 512 + bn + c2];
        }
        __syncthreads();
#pragma unroll
        for (int k = 0; k < 16; ++k)
#pragma unroll
            for (int i = 0; i < 4; ++i)
#pragma unroll
                for (int j = 0; j < 4; ++j)
                    acc[i][j] += As[k][ty * 4 + i] * Bs[k][tx * 4 + j];
        __syncthreads();
    }
#pragma unroll
    for (int i = 0; i < 4; ++i)
#pragma unroll
        for (int j = 0; j < 4; ++j) {
            long o = (long)(bm + ty * 4 + i) * 512 + bn + tx * 4 + j;
            float v = alpha * acc[i][j];
            if (I) v += beta * I[o];
            O[o] = v;
        }
}

// ---------------------------------------------------------------------------
// small utility kernels
// ---------------------------------------------------------------------------
__global__ __launch_bounds__(256) void k_cast_panel(const float* src, long srcLd, long R, long C,
                                                    u16* panel, long pLd) {
    long total = R * C;
    for (long idx = (long)blockIdx.x * 256 + threadIdx.x; idx < total; idx += (long)gridDim.x * 256) {
        long k = idx / C, n = idx % C;
        panel[((k >> 3) * pLd + n) * 8 + (k & 7)] = f2bf(src[k * srcLd + n]);
    }
}

__global__ __launch_bounds__(256) void k_transpose_cast(const float* src, long srcLd, long R, long C,
                                                        u16* panel, long pLd, float* dstFT,
                                                        const float* slots, int sIdx) {
    float scale = (sIdx >= 0) ? slots[sIdx] : 1.0f;
    long total = R * C;
    for (long idx = (long)blockIdx.x * 256 + threadIdx.x; idx < total; idx += (long)gridDim.x * 256) {
        long i = idx / C, j = idx % C;
        float v = src[i * srcLd + j] * scale;
        if (panel) panel[((j >> 3) * pLd + i) * 8 + (j & 7)] = f2bf(v);
        if (dstFT) dstFT[j * R + i] = v;
    }
}

// 4 fused 512x512 scaled transposes (panel + optional fp32 transpose out)
struct T4Args {
    const float* src0; const float* src1; const float* src2; const float* src3;
    long ld0, ld1, ld2, ld3;
    u16 *p0, *p1, *p2, *p3;
    float *f0, *f1, *f2, *f3;
    int s0, s1, s2, s3;
    const float* slots;
};
__global__ __launch_bounds__(256) void k_transpose4(T4Args t) {
    int m = blockIdx.y;
    const float* src; long ld; u16* panel; float* dstFT; int sIdx;
    if (m == 0) { src = t.src0; ld = t.ld0; panel = t.p0; dstFT = t.f0; sIdx = t.s0; }
    else if (m == 1) { src = t.src1; ld = t.ld1; panel = t.p1; dstFT = t.f1; sIdx = t.s1; }
    else if (m == 2) { src = t.src2; ld = t.ld2; panel = t.p2; dstFT = t.f2; sIdx = t.s2; }
    else { src = t.src3; ld = t.ld3; panel = t.p3; dstFT = t.f3; sIdx = t.s3; }
    float scale = (sIdx >= 0) ? t.slots[sIdx] : 1.0f;
    for (long idx = (long)blockIdx.x * 256 + threadIdx.x; idx < 262144; idx += (long)gridDim.x * 256) {
        long i = idx >> 9, j = idx & 511;
        float v = src[i * ld + j] * scale;
        panel[((j >> 3) * 512 + i) * 8 + (j & 7)] = f2bf(v);
        if (dstFT) dstFT[j * 512 + i] = v;
    }
}

// S panel cast + X1 = 2I - S (fp32 + panel), fused
__global__ __launch_bounds__(256) void k_sx1(const float* S, u16* Sp, float* Xf, u16* Xp) {
    for (long idx = (long)blockIdx.x * 256 + threadIdx.x; idx < 262144; idx += (long)gridDim.x * 256) {
        int i = (int)(idx >> 9), j = (int)(idx & 511);
        float sv = S[idx];
        Sp[(((long)(i >> 3)) * 512 + j) * 8 + (i & 7)] = f2bf(sv);
        float v = ((i == j) ? 2.0f : 0.0f) - sv;
        Xf[idx] = v;
        Xp[(((long)(i >> 3)) * 512 + j) * 8 + (i & 7)] = f2bf(v);
    }
}

__global__ void k_fin(float* slots, const float* lg) {
    float lnacc = 0.f, w = 1.f;
    for (int i = 0; i <= 8; ++i) {
        lnacc += w * 0.5f * logf(fmaxf(slots[i], 1e-30f));
        w *= 0.5f;
    }
    float sigma = fmaxf(expf(0.5f * lnacc), 1e-5f);
    float s = sigma + 0.002f;
    slots[32] = 1.0f / s;            // s_inv
    slots[33] = expf(lg[0]) / s;     // gamma * s_inv
}

__global__ __launch_bounds__(256) void k_state0(float* states, const float* state) {
    int i = blockIdx.x * 256 + threadIdx.x;
    if (i < 8192) {
        int b = i >> 9, n = i & 511;
        states[(long)b * 2097664 + n] = state[i];
    }
}

// ---------------------------------------------------------------------------
extern "C" void kernel_launch(void* const* d_in, const int* in_sizes, int n_in,
                              void* d_out, int out_size, void* d_ws, size_t ws_size,
                              hipStream_t stream) {
    (void)in_sizes; (void)n_in; (void)out_size; (void)ws_size;

    const float* u     = (const float*)d_in[0];   // 16 x 4096 x 512
    const float* state = (const float*)d_in[1];   // 16 x 512
    const float* S     = (const float*)d_in[2];   // 512 x 512
    const float* K     = (const float*)d_in[3];   // 1024 x 1024
    const float* lg    = (const float*)d_in[4];   // scalar

    float* out    = (float*)d_out;                // 16 x 4096 x 512
    float* states = out + 33554432L;              // 16 x 4097 x 512
    float* Zb     = out;                          // KS ping (16384x512), overwritten by out-GEMM

    // workspace: persistent panels, then scratch (Za aliases scratch start)
    char* w = (char*)d_ws;
    auto alloc = [&](size_t n) { void* p = w; w += (n + 255) & ~(size_t)255; return p; };
    float* slots = (float*)alloc(256);
    u16* Qall = (u16*)alloc(4L * 262144 * 2);   // Q1..Q4 panels (block p-1 = AT^p)
    u16* W4p  = (u16*)alloc(4L * 262144 * 2);   // W_p = BT@AT^(3-p), p=0..3
    u16* Q8p  = (u16*)alloc(262144L * 2);
    u16* Q16p = (u16*)alloc(262144L * 2);
    u16* CDT  = (u16*)alloc(2L * 262144 * 2);   // [CT;DT]
    float* Qf   = (float*)alloc(4L * 262144 * 4); // Q1..Q4 fp32
    float* W4f  = (float*)alloc(4L * 262144 * 4); // W0..W3 fp32
    float* Q8f  = (float*)alloc(262144L * 4);
    float* Q16f = (float*)alloc(262144L * 4);
    float* Za   = (float*)w;                      // 16384x512 fp32 (32MB), aliases scratch
    float* KTf = (float*)alloc(1024L * 1024 * 4);
    u16*   Kp  = (u16*)  alloc(1024L * 1024 * 2);
    float* Mf  = (float*)alloc(1024L * 1024 * 4);
    u16*   Mp  = (u16*)  alloc(1024L * 1024 * 2);
    float* Mf2 = (float*)alloc(1024L * 1024 * 4);
    u16*   Mp2 = (u16*)  alloc(1024L * 1024 * 2);
    u16*   Sp  = (u16*)  alloc(512L * 512 * 2);
    float* Xaf = (float*)alloc(512L * 512 * 4);
    u16*   Xap = (u16*)  alloc(512L * 512 * 2);
    float* Xbf = (float*)alloc(512L * 512 * 4);
    u16*   Xbp = (u16*)  alloc(512L * 512 * 2);
    float* Pf  = (float*)alloc(512L * 512 * 4);
    u16*   Pp  = (u16*)  alloc(512L * 512 * 2);
    float* Xs  = (float*)alloc(512L * 512 * 4);
    float* T1f = (float*)alloc(1024L * 512 * 4); // [K11@S ; K21@S]
    u16*   T1p = (u16*)  alloc(1024L * 512 * 2); // panel (rows 0..511 = K11@S)
    float* Cmf = T1f + 262144;                   // alias: bottom half = K21@S
    float* Af  = (float*)alloc(512L * 512 * 4);
    float* Bmf = (float*)alloc(512L * 512 * 4);

    auto mkargs = [&]() { GemmArgs a = {}; a.beta = 1.f; a.cScale = 1.f; return a; };
    auto launch_gemm = [&](int M, int N, const GemmArgs& a) {
        dim3 gr(M / 16, N / 128);
        gemm_bf16<<<gr, 64, 0, stream>>>(a);
    };

    hipMemsetAsync(slots, 0, 256, stream);

    // ---- sigma = ||K||_2 via normalized repeated squaring of K^T K --------
    k_transpose_cast<<<4096, 256, 0, stream>>>(K, 1024, 1024, 1024, nullptr, 0, KTf, nullptr, -1);
    k_cast_panel<<<4096, 256, 0, stream>>>(K, 1024, 1024, 1024, Kp, 1024);
    {   GemmArgs a = mkargs();
        a.A1 = KTf; a.a1RS = 1024;
        a.Bp = Kp; a.ldbN = 1024;
        a.Out = Mf; a.oRS = 1024; a.OutP = Mp; a.opLd = 1024;
        a.Kit = 32; a.sumsq = slots + 0;
        launch_gemm(1024, 1024, a);
    }
    {   float* Fs[2] = {Mf, Mf2};
        u16*   Ps[2] = {Mp, Mp2};
        for (int i = 1; i <= 8; ++i) {
            GemmArgs a = mkargs();
            a.A1 = Fs[(i + 1) & 1]; a.a1RS = 1024;
            a.Bp = Ps[(i + 1) & 1]; a.ldbN = 1024;
            a.Out = Fs[i & 1]; a.oRS = 1024; a.OutP = Ps[i & 1]; a.opLd = 1024;
            a.Kit = 32; a.sumsq = slots + i; a.scalePtr = slots + (i - 1);
            launch_gemm(1024, 1024, a);
        }
    }
    k_fin<<<1, 1, 0, stream>>>(slots, lg);

    // ---- Sinv via Newton (3 bf16 iters + 1 fp32 polish) --------------------
    k_sx1<<<1024, 256, 0, stream>>>(S, Sp, Xaf, Xap);
    float* curF = Xaf; u16* curP = Xap; float* nxtF = Xbf; u16* nxtP = Xbp;
    for (int it = 0; it < 3; ++it) {
        GemmArgs a = mkargs();
        a.A1 = S; a.a1RS = 512;
        a.Bp = curP; a.ldbN = 512;
        a.Out = Pf; a.oRS = 512; a.OutP = Pp; a.opLd = 512; a.cScale = -1.f;
        a.Kit = 16;
        launch_gemm(512, 512, a);
        GemmArgs b = mkargs();
        b.A1 = curF; b.a1RS = 512;
        b.Bp = Pp; b.ldbN = 512;
        b.initP = curF; b.iRS = 512; b.beta = 2.f;
        b.Out = nxtF; b.oRS = 512; b.OutP = nxtP; b.opLd = 512;
        b.Kit = 16;
        launch_gemm(512, 512, b);
        float* tf = curF; curF = nxtF; nxtF = tf;
        u16*   tp = curP; curP = nxtP; nxtP = tp;
    }
    gemm_f32_512<<<dim3(8, 8), 256, 0, stream>>>(S, curF, nullptr, Pf, 1.f, 0.f);
    gemm_f32_512<<<dim3(8, 8), 256, 0, stream>>>(curF, Pf, curF, Xs, -1.f, 2.f);

    // ---- A,B,C,D prep ------------------------------------------------------
    {   GemmArgs a = mkargs();   // [T1;Cmf] = [K11;K21] @ S   (merged, M=1024)
        a.A1 = K; a.a1RS = 1024; a.Bp = Sp; a.ldbN = 512;
        a.Out = T1f; a.oRS = 512; a.OutP = T1p; a.opLd = 512; a.Kit = 16;
        launch_gemm(1024, 512, a);
    }
    {   GemmArgs a = mkargs();   // Af = Sinv @ T1  (T1p rows 0..511 = K11@S)
        a.A1 = Xs; a.a1RS = 512; a.Bp = T1p; a.ldbN = 512;
        a.Out = Af; a.oRS = 512; a.Kit = 16;
        launch_gemm(512, 512, a);
    }
    {   GemmArgs a = mkargs();   // Bmf = Sinv @ K12
        a.A1 = Xs; a.a1RS = 512; a.Bp = Kp; a.ldbN = 1024; a.colOff = 512;
        a.Out = Bmf; a.oRS = 512; a.Kit = 16;
        launch_gemm(512, 512, a);
    }
    // fused transposes: Q1 = AT*sinv; W3 = BT*g*sinv; CT*sinv; DT*g*sinv
    {   T4Args t = {};
        t.src0 = Af;  t.ld0 = 512;  t.p0 = Qall;            t.f0 = Qf;             t.s0 = 32;
        t.src1 = Bmf; t.ld1 = 512;  t.p1 = W4p + 3*262144;  t.f1 = W4f + 3*262144; t.s1 = 33;
        t.src2 = Cmf; t.ld2 = 512;  t.p2 = CDT;             t.f2 = nullptr;        t.s2 = 32;
        t.src3 = K + 512L*1024 + 512; t.ld3 = 1024; t.p3 = CDT + 262144; t.f3 = nullptr; t.s3 = 33;
        t.slots = slots;
        k_transpose4<<<dim3(512, 4), 256, 0, stream>>>(t);
    }
    // Q chain: Q2; [Q3;Q4]; Q8; Q16
    {   GemmArgs a = mkargs();
        a.A1 = Qf; a.a1RS = 512; a.Bp = Qall; a.ldbN = 512;
        a.Out = Qf + 262144; a.oRS = 512; a.OutP = Qall + 262144; a.opLd = 512; a.Kit = 16;
        launch_gemm(512, 512, a);                                   // Q2
        a.A1 = Qf; a.Bp = Qall + 262144;
        a.Out = Qf + 2 * 262144; a.OutP = Qall + 2 * 262144;
        launch_gemm(1024, 512, a);                                  // [Q3;Q4]
        a.A1 = Qf + 3 * 262144; a.Bp = Qall + 3 * 262144;
        a.Out = Q8f; a.OutP = Q8p;
        launch_gemm(512, 512, a);                                   // Q8
        a.A1 = Q8f; a.Bp = Q8p;
        a.Out = Q16f; a.OutP = Q16p;
        launch_gemm(512, 512, a);                                   // Q16
    }
    // W chain: W2 = BT@AT; [W0;W1] = [W2;W3]@Q2
    {   GemmArgs a = mkargs();
        a.A1 = W4f + 3 * 262144; a.a1RS = 512; a.Bp = Qall; a.ldbN = 512;
        a.Out = W4f + 2 * 262144; a.oRS = 512; a.OutP = W4p + 2 * 262144; a.opLd = 512; a.Kit = 16;
        launch_gemm(512, 512, a);                                   // W2
        a.A1 = W4f + 2 * 262144; a.Bp = Qall + 262144;
        a.Out = W4f; a.OutP = W4p;
        launch_gemm(1024, 512, a);                                  // [W0;W1]
    }

    // ---- Zloc = Ustack @ W4stack  (16384 x 2048 x 512), MF=1: 512 blocks ---
    {   SArgs a = {};
        a.A1 = u; a.a1BS = 2097152; a.a1RS = 2048; a.a1Shift = 10; a.a1Mask = 1023;
        a.predMask = 1023;
        a.B1 = W4p; a.B2 = W4p; a.K1c = 64; a.Kc = 64;
        a.beta = 1.f;
        a.Out = Za; a.oBS = 0; a.oRS = 512; a.oShift = 14; a.oMask = 16383;
        gemm_staged<1><<<dim3(512, 1, 1), 512, 0, stream>>>(a);
    }
    // state fixup: Zloc[b,0] += state @ Q4
    {   GemmArgs f = mkargs();
        f.A1 = state; f.a1RS = 512;
        f.Bp = Qall + 3 * 262144; f.ldbN = 512;
        f.initP = Za; f.iRS = 524288; f.beta = 1.f;
        f.Out = Za; f.oRS = 524288; f.Kit = 16;
        launch_gemm(16, 512, f);
    }
    k_state0<<<32, 256, 0, stream>>>(states, state);

    // ---- Kogge-Stone: rounds d=1 (Q4), d=2 (Q8); round d=4 (Q16) -> states -
    auto ks = [&](const float* src, float* dst, int d, const u16* gen) {
        SArgs a = {};
        a.A1 = src; a.a1BS = 0; a.a1RS = 512; a.a1Shift = 14; a.a1Mask = 16383;
        a.shiftA = d; a.predLow = d; a.predMask = 1023;
        a.B1 = gen; a.B2 = gen; a.K1c = 16; a.Kc = 16;
        a.initP = src; a.iBS = 0; a.iRS = 512; a.iShift = 14; a.iMask = 16383; a.beta = 1.f;
        a.Out = dst; a.oBS = 0; a.oRS = 512; a.oShift = 14; a.oMask = 16383;
        gemm_staged<1><<<dim3(512, 1, 1), 512, 0, stream>>>(a);
    };
    ks(Za, Zb, 1, Qall + 3 * 262144);
    ks(Zb, Za, 2, Q8p);
    {   // round 3: dst = states[b][4c+4] (strided)
        SArgs a = {};
        a.A1 = Za; a.a1BS = 0; a.a1RS = 512; a.a1Shift = 14; a.a1Mask = 16383;
        a.shiftA = 4; a.predLow = 4; a.predMask = 1023;
        a.B1 = Q16p; a.B2 = Q16p; a.K1c = 16; a.Kc = 16;
        a.initP = Za; a.iBS = 0; a.iRS = 512; a.iShift = 14; a.iMask = 16383; a.beta = 1.f;
        a.Out = states + 2048; a.oBS = 2097664; a.oRS = 2048; a.oShift = 10; a.oMask = 1023;
        gemm_staged<1><<<dim3(512, 1, 1), 512, 0, stream>>>(a);
    }

    // ---- phase C: states[4c+s] = [x_c; u_0..u_{s-1}] @ [Q_s; Wtail], s=1..3 -
    // flat grid 768, s = 3 - bx/256 (longest group first, contiguous s)
    {   SArgs a = {};
        a.A1 = states; a.a1BS = 2097664; a.a1RS = 2048; a.a1Shift = 10; a.a1Mask = 1023;
        a.predMask = 1023;
        a.A2 = u; a.a2BS = 2097152; a.a2RS = 2048; a.a2Shift = 10; a.a2Mask = 1023;
        a.B1 = Qall; a.B2 = W4p; a.K1c = 16; a.Kc = 0;
        a.beta = 1.f;
        a.Out = states; a.oBS = 2097664; a.oRS = 2048; a.oShift = 10; a.oMask = 1023;
        a.sMode = 1;
        gemm_staged<2><<<dim3(768, 1, 1), 512, 0, stream>>>(a);
    }

    // ---- out = states_pre @ CT + u @ DT  (65536 x 1024 x 512), MF=2 --------
    {   SArgs a = {};
        a.A1 = states; a.a1BS = 2097664; a.a1RS = 512; a.a1Shift = 12; a.a1Mask = 4095;
        a.predMask = 4095;
        a.A2 = u; a.a2BS = 2097152; a.a2RS = 512; a.a2Shift = 12; a.a2Mask = 4095;
        a.B1 = CDT; a.B2 = CDT + 262144; a.K1c = 16; a.Kc = 32;
        a.beta = 1.f;
        a.Out = out; a.oBS = 2097152; a.oRS = 512; a.oShift = 12; a.oMask = 4095;
        gemm_staged<2><<<dim3(1024, 1, 1), 512, 0, stream>>>(a);
    }
}